// Round 1
// baseline (225.461 us; speedup 1.0000x reference)
//
#include <hip/hip_runtime.h>

typedef __bf16 bf16;
typedef __bf16 bf16x4 __attribute__((ext_vector_type(4)));
typedef __bf16 bf16x8 __attribute__((ext_vector_type(8)));
typedef float f32x4 __attribute__((ext_vector_type(4)));

#define B_ 2
#define H_ 8
#define L_ 2048
#define D_ 128
#define F_ 128
#define QT 64
#define KT 64
#define NKT (L_ / KT)

// LDS layout (bytes):
//  sQ   @ 0      : 64x128 bf16 = 16384   (epilogue: sOh 64x128 = 16384)
//  sK   @ 16384  : 64x128 bf16 = 16384   (epilogue: sO2t 128x136 = 34816 spans sK+sVt)
//  sVt  @ 32768  : 128x72 bf16 = 18432
//  sP   @ 51200  : 64x66  bf16 = 8448
#define SMEM_BYTES 59648

__global__ __launch_bounds__(256, 2)
void attn_fused_kernel(const float* __restrict__ XQ, const float* __restrict__ XK,
                       const float* __restrict__ XV, const int* __restrict__ mask,
                       const float* __restrict__ WQ, const float* __restrict__ WK,
                       const float* __restrict__ WV, const float* __restrict__ Om,
                       float* __restrict__ out)
{
    __shared__ __align__(16) char smem_raw[SMEM_BYTES];
    __shared__ __align__(16) float g_s[128];

    bf16* sQ   = (bf16*)smem_raw;                 // 64 x 128
    bf16* sK   = (bf16*)(smem_raw + 16384);       // 64 x 128
    bf16* sVt  = (bf16*)(smem_raw + 32768);       // 128 x 72 (f-major, padded)
    bf16* sP   = (bf16*)(smem_raw + 51200);       // 64 x 66 (padded)
    bf16* sOh  = (bf16*)smem_raw;                 // 64 x 128 (epilogue)
    bf16* sO2t = (bf16*)(smem_raw + 16384);       // 128 x 136 (epilogue)

    const int tid  = threadIdx.x;
    const int wave = tid >> 6;
    const int lane = tid & 63;
    const int c    = lane & 15;   // MFMA n-index (B free dim) / A m-index
    const int quad = lane >> 4;
    const int qt = blockIdx.x, h = blockIdx.y, b = blockIdx.z;
    const int q0 = qt * QT;

    // g[d] = diag(W_Q)[h,d] * diag(W_K)[h,d] * 1/sqrt(D)
    if (tid < 128) {
        int d = tid;
        float wq = WQ[(h * D_ + d) * D_ + d];
        float wk = WK[(h * D_ + d) * D_ + d];
        g_s[d] = wq * wk * 0.08838834764831845f;
    }
    __syncthreads();

    // Stage Q tile (scaled, bf16), rows q0..q0+63
    {
        const int d4 = (tid & 31) * 4;
        const int r8 = tid >> 5;
        float4 gv = *(const float4*)&g_s[d4];
        #pragma unroll
        for (int i = 0; i < 8; ++i) {
            int q = r8 + i * 8;
            float4 v = *(const float4*)(XQ + ((b * L_ + q0 + q) * D_ + d4));
            bf16x4 w;
            w[0] = (bf16)(v.x * gv.x); w[1] = (bf16)(v.y * gv.y);
            w[2] = (bf16)(v.z * gv.z); w[3] = (bf16)(v.w * gv.w);
            *(bf16x4*)(sQ + q * 128 + d4) = w;
        }
    }

    f32x4 oacc[8];
    #pragma unroll
    for (int i = 0; i < 8; ++i)
        #pragma unroll
        for (int r = 0; r < 4; ++r) oacc[i][r] = 0.f;
    float lsum[4] = {0.f, 0.f, 0.f, 0.f};

    for (int kt = 0; kt < NKT; ++kt) {
        const int k0 = kt * KT;
        __syncthreads();   // previous iter's sK/sVt/sP reads complete

        // Stage K tile (row-major bf16)
        {
            const int d4 = (tid & 31) * 4;
            const int r8 = tid >> 5;
            #pragma unroll
            for (int i = 0; i < 8; ++i) {
                int k = r8 + i * 8;
                float4 v = *(const float4*)(XK + ((b * L_ + k0 + k) * D_ + d4));
                bf16x4 w;
                w[0] = (bf16)v.x; w[1] = (bf16)v.y; w[2] = (bf16)v.z; w[3] = (bf16)v.w;
                *(bf16x4*)(sK + k * 128 + d4) = w;
            }
            // Stage V^T: sVt[f][k], f-major threads (coalesced global reads)
            const int f   = tid & 127;
            const int grp = tid >> 7;
            #pragma unroll
            for (int i = 0; i < 8; ++i) {
                int k4 = grp * 32 + i * 4;
                bf16x4 w;
                #pragma unroll
                for (int j = 0; j < 4; ++j)
                    w[j] = (bf16)XV[(b * L_ + k0 + k4 + j) * F_ + f];
                *(bf16x4*)(sVt + f * 72 + k4) = w;
            }
        }
        __syncthreads();

        // S = Qg @ K^T  (wave handles m-rows [wave*16, wave*16+16), all 64 n-cols)
        bf16x8 afrag[4];
        const bf16* qrow = sQ + (wave * 16 + c) * 128;
        #pragma unroll
        for (int kc = 0; kc < 4; ++kc)
            afrag[kc] = *(const bf16x8*)(qrow + kc * 32 + quad * 8);

        f32x4 sacc[4];
        #pragma unroll
        for (int nt = 0; nt < 4; ++nt)
            #pragma unroll
            for (int r = 0; r < 4; ++r) sacc[nt][r] = 0.f;

        #pragma unroll
        for (int nt = 0; nt < 4; ++nt) {
            const bf16* krow = sK + (nt * 16 + c) * 128;
            #pragma unroll
            for (int kc = 0; kc < 4; ++kc) {
                bf16x8 bfrag = *(const bf16x8*)(krow + kc * 32 + quad * 8);
                sacc[nt] = __builtin_amdgcn_mfma_f32_16x16x32_bf16(afrag[kc], bfrag, sacc[nt], 0, 0, 0);
            }
        }

        // mask + exp (no max subtraction needed: |S| << 1) + write P to LDS
        const int qrow0 = q0 + wave * 16 + quad * 4;
        #pragma unroll
        for (int nt = 0; nt < 4; ++nt) {
            int kg = k0 + nt * 16 + c;
            const int* mrow = mask + (size_t)b * L_ * L_ + (size_t)qrow0 * L_ + kg;
            #pragma unroll
            for (int r = 0; r < 4; ++r) {
                int mv = mrow[r * L_];
                float p = mv ? __expf(sacc[nt][r]) : 0.f;
                lsum[r] += p;
                sP[(wave * 16 + quad * 4 + r) * 66 + nt * 16 + c] = (bf16)p;
            }
        }
        __syncthreads();

        // O += P @ V  (A-frag from sP via 4B-aligned loads; B-frag from sVt, 16B aligned)
        bf16x8 pfrag[2];
        {
            const bf16* prow = sP + (wave * 16 + c) * 66;
            #pragma unroll
            for (int kc = 0; kc < 2; ++kc) {
                union { unsigned int u[4]; bf16x8 v; } t;
                const unsigned int* p32 = (const unsigned int*)(prow + kc * 32 + quad * 8);
                t.u[0] = p32[0]; t.u[1] = p32[1]; t.u[2] = p32[2]; t.u[3] = p32[3];
                pfrag[kc] = t.v;
            }
        }
        #pragma unroll
        for (int nt = 0; nt < 8; ++nt) {
            const bf16* vrow = sVt + (nt * 16 + c) * 72;
            #pragma unroll
            for (int kc = 0; kc < 2; ++kc) {
                bf16x8 bfrag = *(const bf16x8*)(vrow + kc * 32 + quad * 8);
                oacc[nt] = __builtin_amdgcn_mfma_f32_16x16x32_bf16(pfrag[kc], bfrag, oacc[nt], 0, 0, 0);
            }
        }
    }

    // Row-sum reduce across the 16 n-lanes; invert once.
    #pragma unroll
    for (int r = 0; r < 4; ++r) {
        float v = lsum[r];
        v += __shfl_xor(v, 1); v += __shfl_xor(v, 2);
        v += __shfl_xor(v, 4); v += __shfl_xor(v, 8);
        lsum[r] = 1.0f / v;
    }

    __syncthreads();   // all sQ/sK/sVt reads complete; safe to repurpose

    // dv diag into g_s (reused)
    if (tid < 128) {
        int f = tid;
        g_s[f] = WV[(h * F_ + f) * F_ + f];
    }
    // Oh (normalized, bf16) into sOh
    #pragma unroll
    for (int nt = 0; nt < 8; ++nt)
        #pragma unroll
        for (int r = 0; r < 4; ++r) {
            float v = oacc[nt][r] * lsum[r];
            sOh[(wave * 16 + quad * 4 + r) * 128 + nt * 16 + c] = (bf16)v;
        }
    __syncthreads();

    // Stage O2^T for this head: sO2t[f][f'] = O[h*128+f'][f] * dv[f']
    {
        const int f   = tid & 127;
        const int grp = tid >> 7;
        #pragma unroll
        for (int i = 0; i < 16; ++i) {
            int fp4 = grp * 64 + i * 4;
            bf16x4 w;
            #pragma unroll
            for (int j = 0; j < 4; ++j) {
                int x = fp4 + j;
                w[j] = (bf16)(Om[(h * F_ + x) * F_ + f] * g_s[x]);
            }
            *(bf16x4*)(sO2t + f * 136 + fp4) = w;
        }
    }
    __syncthreads();

    // out_partial = Oh @ O2  (64x128x128), atomic-accumulate over heads
    bf16x8 afr[4];
    const bf16* ohrow = sOh + (wave * 16 + c) * 128;
    #pragma unroll
    for (int kc = 0; kc < 4; ++kc)
        afr[kc] = *(const bf16x8*)(ohrow + kc * 32 + quad * 8);

    #pragma unroll
    for (int nt = 0; nt < 8; ++nt) {
        f32x4 pacc;
        #pragma unroll
        for (int r = 0; r < 4; ++r) pacc[r] = 0.f;
        const bf16* orow = sO2t + (nt * 16 + c) * 136;
        #pragma unroll
        for (int kc = 0; kc < 4; ++kc) {
            bf16x8 bfrag = *(const bf16x8*)(orow + kc * 32 + quad * 8);
            pacc = __builtin_amdgcn_mfma_f32_16x16x32_bf16(afr[kc], bfrag, pacc, 0, 0, 0);
        }
        #pragma unroll
        for (int r = 0; r < 4; ++r) {
            int qg = q0 + wave * 16 + quad * 4 + r;
            atomicAdd(out + ((b * L_ + qg) * F_ + nt * 16 + c), pacc[r]);
        }
    }
}

extern "C" void kernel_launch(void* const* d_in, const int* in_sizes, int n_in,
                              void* d_out, int out_size, void* d_ws, size_t ws_size,
                              hipStream_t stream) {
    const float* XQ   = (const float*)d_in[0];
    const float* XK   = (const float*)d_in[1];
    const float* XV   = (const float*)d_in[2];
    const int*   mask = (const int*)d_in[3];
    const float* WQ   = (const float*)d_in[4];
    const float* WK   = (const float*)d_in[5];
    const float* WV   = (const float*)d_in[6];
    const float* Om   = (const float*)d_in[7];
    float* out = (float*)d_out;

    hipMemsetAsync(out, 0, (size_t)out_size * sizeof(float), stream);
    dim3 grid(L_ / QT, H_, B_);
    attn_fused_kernel<<<grid, 256, 0, stream>>>(XQ, XK, XV, mask, WQ, WK, WV, Om, out);
}

// Round 2
// 223.545 us; speedup vs baseline: 1.0086x; 1.0086x over previous
//
#include <hip/hip_runtime.h>

typedef __bf16 bf16;
typedef __bf16 bf16x4 __attribute__((ext_vector_type(4)));
typedef __bf16 bf16x8 __attribute__((ext_vector_type(8)));
typedef float f32x4 __attribute__((ext_vector_type(4)));

#define B_ 2
#define H_ 8
#define L_ 2048
#define D_ 128
#define F_ 128
#define QT 64
#define KT 64
#define NKT (L_ / KT)

// Padded strides (bf16 elements). 136 -> 68 dwords = 4 mod 32 -> 2-way (free).
// 72 -> 36 dwords = 4 mod 32 -> 2-way (free). All keep 16B row alignment.
#define SK_STRIDE  136
#define SVT_STRIDE 72
#define SP_STRIDE  72
#define SOH_STRIDE 136
#define SO2_STRIDE 136

// main phase : sK [64][136] @0      (17408 B)
//              sVt [128][72] @17408 (18432 B)
//              sP  [64][72]  @35840 ( 9216 B)   total 45056
// epilogue   : sOh [64][136] @0     (17408 B)
//              sO2t[128][136]@17408 (34816 B)   total 52224
#define SMEM_BYTES 52224

__global__ __launch_bounds__(256, 3)
void attn_fused_kernel(const float* __restrict__ XQ, const float* __restrict__ XK,
                       const float* __restrict__ XV, const int* __restrict__ mask,
                       const float* __restrict__ WQ, const float* __restrict__ WK,
                       const float* __restrict__ WV, const float* __restrict__ Om,
                       float* __restrict__ out)
{
    __shared__ __align__(16) char smem[SMEM_BYTES];
    __shared__ __align__(16) float g_s[128];

    bf16* sK   = (bf16*)smem;
    bf16* sVt  = (bf16*)(smem + 17408);
    bf16* sP   = (bf16*)(smem + 35840);
    bf16* sOh  = (bf16*)smem;
    bf16* sO2t = (bf16*)(smem + 17408);

    const int tid  = threadIdx.x;
    const int wave = tid >> 6;
    const int lane = tid & 63;
    const int c    = lane & 15;
    const int quad = lane >> 4;
    const int qt = blockIdx.x, h = blockIdx.y, b = blockIdx.z;
    const int q0 = qt * QT;

    // staging thread mappings
    const int d4  = (tid & 31) * 4;   // K-staging column (floats)
    const int r8  = tid >> 5;         // K-staging row base
    const int fv  = tid & 127;        // V-staging f index
    const int grp = tid >> 7;         // V-staging k-group

    // g[d] = diag(W_Q)*diag(W_K)/sqrt(D)
    if (tid < 128) {
        float wq = WQ[(h * D_ + tid) * D_ + tid];
        float wk = WK[(h * D_ + tid) * D_ + tid];
        g_s[tid] = wq * wk * 0.08838834764831845f;
    }
    __syncthreads();

    // Q fragments held in registers for the whole K loop (loop-invariant).
    bf16x8 qfrag[4];
    {
        const float* qrow = XQ + (size_t)(b * L_ + q0 + wave * 16 + c) * D_;
        #pragma unroll
        for (int kc = 0; kc < 4; ++kc) {
            int d0 = kc * 32 + quad * 8;
            float4 v0 = *(const float4*)(qrow + d0);
            float4 v1 = *(const float4*)(qrow + d0 + 4);
            float4 g0 = *(const float4*)(g_s + d0);
            float4 g1 = *(const float4*)(g_s + d0 + 4);
            bf16x8 w;
            w[0] = (bf16)(v0.x * g0.x); w[1] = (bf16)(v0.y * g0.y);
            w[2] = (bf16)(v0.z * g0.z); w[3] = (bf16)(v0.w * g0.w);
            w[4] = (bf16)(v1.x * g1.x); w[5] = (bf16)(v1.y * g1.y);
            w[6] = (bf16)(v1.z * g1.z); w[7] = (bf16)(v1.w * g1.w);
            qfrag[kc] = w;
        }
    }

    // K/V register prefetch buffers
    float4 kpre[8];
    bf16x4 vpre[8];
    {
        const int k0 = 0;
        #pragma unroll
        for (int i = 0; i < 8; ++i)
            kpre[i] = *(const float4*)(XK + (size_t)(b * L_ + k0 + r8 + i * 8) * D_ + d4);
        #pragma unroll
        for (int i = 0; i < 8; ++i) {
            int k4 = grp * 32 + i * 4;
            bf16x4 w;
            #pragma unroll
            for (int j = 0; j < 4; ++j)
                w[j] = (bf16)XV[(size_t)(b * L_ + k0 + k4 + j) * F_ + fv];
            vpre[i] = w;
        }
    }

    f32x4 oacc[8];
    #pragma unroll
    for (int i = 0; i < 8; ++i)
        #pragma unroll
        for (int r = 0; r < 4; ++r) oacc[i][r] = 0.f;
    float lsum[4] = {0.f, 0.f, 0.f, 0.f};

    for (int kt = 0; kt < NKT; ++kt) {
        const int k0 = kt * KT;
        __syncthreads();   // all reads of prev sK/sVt/sP complete

        // regs -> LDS
        #pragma unroll
        for (int i = 0; i < 8; ++i) {
            int k = r8 + i * 8;
            bf16x4 w;
            w[0] = (bf16)kpre[i].x; w[1] = (bf16)kpre[i].y;
            w[2] = (bf16)kpre[i].z; w[3] = (bf16)kpre[i].w;
            *(bf16x4*)(sK + k * SK_STRIDE + d4) = w;
        }
        #pragma unroll
        for (int i = 0; i < 8; ++i) {
            int k4 = grp * 32 + i * 4;
            *(bf16x4*)(sVt + fv * SVT_STRIDE + k4) = vpre[i];
        }
        __syncthreads();

        // prefetch next tile's globals (overlaps with MFMA below)
        if (kt + 1 < NKT) {
            const int kn = k0 + KT;
            #pragma unroll
            for (int i = 0; i < 8; ++i)
                kpre[i] = *(const float4*)(XK + (size_t)(b * L_ + kn + r8 + i * 8) * D_ + d4);
            #pragma unroll
            for (int i = 0; i < 8; ++i) {
                int k4 = grp * 32 + i * 4;
                bf16x4 w;
                #pragma unroll
                for (int j = 0; j < 4; ++j)
                    w[j] = (bf16)XV[(size_t)(b * L_ + kn + k4 + j) * F_ + fv];
                vpre[i] = w;
            }
        }

        // prefetch mask ints (overlap with S-MFMA)
        const int qrow0 = q0 + wave * 16 + quad * 4;
        int mv[4][4];
        {
            const int* mbase = mask + (size_t)b * L_ * L_ + (size_t)qrow0 * L_ + k0 + c;
            #pragma unroll
            for (int nt = 0; nt < 4; ++nt)
                #pragma unroll
                for (int r = 0; r < 4; ++r)
                    mv[nt][r] = mbase[(size_t)r * L_ + nt * 16];
        }

        // S = Qg @ K^T
        f32x4 sacc[4];
        #pragma unroll
        for (int nt = 0; nt < 4; ++nt)
            #pragma unroll
            for (int r = 0; r < 4; ++r) sacc[nt][r] = 0.f;

        #pragma unroll
        for (int nt = 0; nt < 4; ++nt) {
            const bf16* krow = sK + (nt * 16 + c) * SK_STRIDE;
            #pragma unroll
            for (int kc = 0; kc < 4; ++kc) {
                bf16x8 bfrag = *(const bf16x8*)(krow + kc * 32 + quad * 8);
                sacc[nt] = __builtin_amdgcn_mfma_f32_16x16x32_bf16(qfrag[kc], bfrag, sacc[nt], 0, 0, 0);
            }
        }

        // mask + exp (scores tiny: no max subtraction needed) -> P in LDS
        #pragma unroll
        for (int nt = 0; nt < 4; ++nt) {
            #pragma unroll
            for (int r = 0; r < 4; ++r) {
                float p = mv[nt][r] ? __expf(sacc[nt][r]) : 0.f;
                lsum[r] += p;
                sP[(wave * 16 + quad * 4 + r) * SP_STRIDE + nt * 16 + c] = (bf16)p;
            }
        }
        // pfrag reads only this wave's own sP rows -> LDS drain, no barrier
        asm volatile("s_waitcnt lgkmcnt(0)" ::: "memory");

        bf16x8 pfrag[2];
        const bf16* prow = sP + (wave * 16 + c) * SP_STRIDE;
        #pragma unroll
        for (int kc = 0; kc < 2; ++kc)
            pfrag[kc] = *(const bf16x8*)(prow + kc * 32 + quad * 8);

        #pragma unroll
        for (int nt = 0; nt < 8; ++nt) {
            const bf16* vrow = sVt + (nt * 16 + c) * SVT_STRIDE;
            #pragma unroll
            for (int kc = 0; kc < 2; ++kc) {
                bf16x8 bfrag = *(const bf16x8*)(vrow + kc * 32 + quad * 8);
                oacc[nt] = __builtin_amdgcn_mfma_f32_16x16x32_bf16(pfrag[kc], bfrag, oacc[nt], 0, 0, 0);
            }
        }
    }

    // 1 / row-sum
    #pragma unroll
    for (int r = 0; r < 4; ++r) {
        float v = lsum[r];
        v += __shfl_xor(v, 1); v += __shfl_xor(v, 2);
        v += __shfl_xor(v, 4); v += __shfl_xor(v, 8);
        lsum[r] = 1.0f / v;
    }

    __syncthreads();   // all main-phase LDS reads + g_s reads done

    if (tid < 128)
        g_s[tid] = WV[(h * F_ + tid) * F_ + tid];

    #pragma unroll
    for (int nt = 0; nt < 8; ++nt)
        #pragma unroll
        for (int r = 0; r < 4; ++r) {
            float v = oacc[nt][r] * lsum[r];
            sOh[(wave * 16 + quad * 4 + r) * SOH_STRIDE + nt * 16 + c] = (bf16)v;
        }
    __syncthreads();

    // stage O2^T: sO2t[f][f'] = O[h*128+f'][f] * dv[f']
    #pragma unroll
    for (int i = 0; i < 16; ++i) {
        int fp4 = grp * 64 + i * 4;
        bf16x4 w;
        #pragma unroll
        for (int j = 0; j < 4; ++j) {
            int x = fp4 + j;
            w[j] = (bf16)(Om[(h * F_ + x) * F_ + fv] * g_s[x]);
        }
        *(bf16x4*)(sO2t + fv * SO2_STRIDE + fp4) = w;
    }
    __syncthreads();

    // out_partial = Oh @ O2, atomic accumulate over heads
    bf16x8 afr[4];
    const bf16* ohrow = sOh + (wave * 16 + c) * SOH_STRIDE;
    #pragma unroll
    for (int kc = 0; kc < 4; ++kc)
        afr[kc] = *(const bf16x8*)(ohrow + kc * 32 + quad * 8);

    #pragma unroll
    for (int nt = 0; nt < 8; ++nt) {
        f32x4 pacc;
        #pragma unroll
        for (int r = 0; r < 4; ++r) pacc[r] = 0.f;
        const bf16* orow = sO2t + (nt * 16 + c) * SO2_STRIDE;
        #pragma unroll
        for (int kc = 0; kc < 4; ++kc) {
            bf16x8 bfrag = *(const bf16x8*)(orow + kc * 32 + quad * 8);
            pacc = __builtin_amdgcn_mfma_f32_16x16x32_bf16(afr[kc], bfrag, pacc, 0, 0, 0);
        }
        #pragma unroll
        for (int r = 0; r < 4; ++r) {
            int qg = q0 + wave * 16 + quad * 4 + r;
            atomicAdd(out + ((size_t)(b * L_ + qg) * F_ + nt * 16 + c), pacc[r]);
        }
    }
}

extern "C" void kernel_launch(void* const* d_in, const int* in_sizes, int n_in,
                              void* d_out, int out_size, void* d_ws, size_t ws_size,
                              hipStream_t stream) {
    const float* XQ   = (const float*)d_in[0];
    const float* XK   = (const float*)d_in[1];
    const float* XV   = (const float*)d_in[2];
    const int*   mask = (const int*)d_in[3];
    const float* WQ   = (const float*)d_in[4];
    const float* WK   = (const float*)d_in[5];
    const float* WV   = (const float*)d_in[6];
    const float* Om   = (const float*)d_in[7];
    float* out = (float*)d_out;

    hipMemsetAsync(out, 0, (size_t)out_size * sizeof(float), stream);
    dim3 grid(L_ / QT, H_, B_);
    attn_fused_kernel<<<grid, 256, 0, stream>>>(XQ, XK, XV, mask, WQ, WK, WV, Om, out);
}

// Round 3
// 170.440 us; speedup vs baseline: 1.3228x; 1.3116x over previous
//
#include <hip/hip_runtime.h>

typedef __bf16 bf16;
typedef __bf16 bf16x4 __attribute__((ext_vector_type(4)));
typedef __bf16 bf16x8 __attribute__((ext_vector_type(8)));
typedef float f32x4 __attribute__((ext_vector_type(4)));
typedef unsigned int u32;
typedef unsigned long long u64;

#define B_ 2
#define H_ 8
#define L_ 2048
#define D_ 128
#define F_ 128
#define QT 64
#define KT 64
#define NKT (L_ / KT)

// workspace layout (bytes)
#define WS_KB 0u            // Kb  : bf16 [b][k][16B-chunk swizzled], 2*2048*256B = 1 MB
#define WS_VT (1u << 20)    // Vtb : bf16 tiles [b][kt][f][chunk swz], 64 * 16 KB = 1 MB
#define WS_MB (2u << 20)    // bits: u64 [b][q][kt], 2*2048*32*8 = 1 MB

// LDS main phase: sK0@0, sK1@16384, sV0@32768, sV1@49152 (16 KB each, unpadded,
// XOR-swizzled), sP@65536 (64x72 bf16 = 9216). Total 74752 -> 2 blocks/CU.
// Epilogue aliases: sOh@0 (64x136), sO2t@17408 (128x136).
#define SMEM_BYTES 74752
#define SP_OFF 65536
#define SP_STRIDE 72
#define SOH_STRIDE 136
#define SO2_STRIDE 136

__device__ __forceinline__ void dma16(const void* g, void* l) {
    __builtin_amdgcn_global_load_lds(
        (const __attribute__((address_space(1))) u32*)g,
        (__attribute__((address_space(3))) u32*)l, 16, 0, 0);
}

// ---- prep: K -> bf16, 16B chunks XOR-swizzled within each 256B row ----
__global__ __launch_bounds__(256) void prep_k(const float* __restrict__ XK, bf16* __restrict__ Kb) {
    int gid = blockIdx.x * 256 + threadIdx.x;     // 65536 = 4096 rows * 16 chunks
    int row = gid >> 4;                           // b*2048 + k
    int j   = gid & 15;
    const float* src = XK + (size_t)row * 128 + j * 8;
    float4 v0 = *(const float4*)src;
    float4 v1 = *(const float4*)(src + 4);
    bf16x8 w;
    w[0] = (bf16)v0.x; w[1] = (bf16)v0.y; w[2] = (bf16)v0.z; w[3] = (bf16)v0.w;
    w[4] = (bf16)v1.x; w[5] = (bf16)v1.y; w[6] = (bf16)v1.z; w[7] = (bf16)v1.w;
    int jp = j ^ (row & 15);
    *(bf16x8*)(Kb + (size_t)row * 128 + jp * 8) = w;
}

// ---- prep: V -> V^T bf16 tiles [b][kt][f][64k], 16B chunks swizzled by f&7 ----
__global__ __launch_bounds__(256) void prep_v(const float* __restrict__ XV, bf16* __restrict__ Vtb) {
    __shared__ bf16 sT[64 * 128];
    int tile = blockIdx.x;                        // b*32 + kt
    int b = tile >> 5, kt = tile & 31;
    int k0 = kt * 64;
    int tid = threadIdx.x;
    int f4 = (tid & 31) * 4, kr = tid >> 5;
    #pragma unroll
    for (int i = 0; i < 8; ++i) {
        int k = kr + i * 8;
        float4 v = *(const float4*)(XV + (size_t)(b * L_ + k0 + k) * F_ + f4);
        bf16x4 w;
        w[0] = (bf16)v.x; w[1] = (bf16)v.y; w[2] = (bf16)v.z; w[3] = (bf16)v.w;
        *(bf16x4*)(sT + k * 128 + f4) = w;
    }
    __syncthreads();
    bf16* out = Vtb + (size_t)tile * (128 * 64);
    #pragma unroll
    for (int i = 0; i < 4; ++i) {
        int cid = tid * 4 + i;                    // 0..1023 = f*8 + j
        int f = cid >> 3, j = cid & 7;
        bf16x8 w;
        #pragma unroll
        for (int jj = 0; jj < 8; ++jj) w[jj] = sT[(j * 8 + jj) * 128 + f];
        *(bf16x8*)(out + f * 64 + (j ^ (f & 7)) * 8) = w;
    }
}

// ---- prep: mask int32 -> bitpacked u64 via ballot ----
__global__ __launch_bounds__(256) void prep_mask(const int* __restrict__ mask, u64* __restrict__ bits) {
    size_t gid = (size_t)blockIdx.x * 256 + threadIdx.x;   // 8.4M
    int m = mask[gid];
    u64 bal = __ballot(m != 0);
    if ((threadIdx.x & 63) == 0) bits[gid >> 6] = bal;
}

// ---- main fused kernel ----
__global__ __launch_bounds__(256, 2)
void attn_fused_kernel(const float* __restrict__ XQ, const bf16* __restrict__ Kb,
                       const bf16* __restrict__ Vtb, const u64* __restrict__ bits,
                       const float* __restrict__ WQ, const float* __restrict__ WK,
                       const float* __restrict__ WV, const float* __restrict__ Om,
                       float* __restrict__ out)
{
    __shared__ __align__(16) char smem[SMEM_BYTES];
    __shared__ __align__(16) float g_s[128];

    bf16* sK0 = (bf16*)smem;
    bf16* sK1 = (bf16*)(smem + 16384);
    bf16* sV0 = (bf16*)(smem + 32768);
    bf16* sV1 = (bf16*)(smem + 49152);
    bf16* sP  = (bf16*)(smem + SP_OFF);
    bf16* sOh  = (bf16*)smem;
    bf16* sO2t = (bf16*)(smem + 17408);

    const int tid  = threadIdx.x;
    const int wave = tid >> 6;
    const int lane = tid & 63;
    const int c    = lane & 15;
    const int quad = lane >> 4;
    const int qt = blockIdx.x, h = blockIdx.y, b = blockIdx.z;
    const int q0 = qt * QT;
    const int fv  = tid & 127;       // epilogue staging f index
    const int grp = tid >> 7;

    // g[d] = diag(W_Q)*diag(W_K)/sqrt(D)
    if (tid < 128) {
        float wq = WQ[(h * D_ + tid) * D_ + tid];
        float wk = WK[(h * D_ + tid) * D_ + tid];
        g_s[tid] = wq * wk * 0.08838834764831845f;
    }
    __syncthreads();

    const char* gKbase = (const char*)Kb + (size_t)(b * L_) * 256;       // 16 KB per tile
    const char* gVbase = (const char*)Vtb + (size_t)(b * NKT) * 16384;   // 16 KB per tile

    // DMA tile 0 into buffer 0
    #pragma unroll
    for (int i = 0; i < 4; ++i) dma16(gKbase + i * 4096 + tid * 16, (char*)sK0 + i * 4096 + tid * 16);
    #pragma unroll
    for (int i = 0; i < 4; ++i) dma16(gVbase + i * 4096 + tid * 16, (char*)sV0 + i * 4096 + tid * 16);

    // Q fragments in registers for the whole loop (scaled by g, bf16)
    bf16x8 qfrag[4];
    {
        const float* qrow = XQ + (size_t)(b * L_ + q0 + wave * 16 + c) * D_;
        #pragma unroll
        for (int kc = 0; kc < 4; ++kc) {
            int d0 = kc * 32 + quad * 8;
            float4 v0 = *(const float4*)(qrow + d0);
            float4 v1 = *(const float4*)(qrow + d0 + 4);
            float4 g0 = *(const float4*)(g_s + d0);
            float4 g1 = *(const float4*)(g_s + d0 + 4);
            bf16x8 w;
            w[0] = (bf16)(v0.x * g0.x); w[1] = (bf16)(v0.y * g0.y);
            w[2] = (bf16)(v0.z * g0.z); w[3] = (bf16)(v0.w * g0.w);
            w[4] = (bf16)(v1.x * g1.x); w[5] = (bf16)(v1.y * g1.y);
            w[6] = (bf16)(v1.z * g1.z); w[7] = (bf16)(v1.w * g1.w);
            qfrag[kc] = w;
        }
    }

    const int qrow0 = q0 + wave * 16 + quad * 4;
    const u64* mbase0 = bits + (size_t)(b * L_ + qrow0) * NKT;

    f32x4 oacc[8];
    #pragma unroll
    for (int i = 0; i < 8; ++i)
        #pragma unroll
        for (int r = 0; r < 4; ++r) oacc[i][r] = 0.f;
    float lsum[4] = {0.f, 0.f, 0.f, 0.f};

    #pragma unroll 2
    for (int kt = 0; kt < NKT; ++kt) {
        bf16* sK  = (kt & 1) ? sK1 : sK0;
        bf16* sV  = (kt & 1) ? sV1 : sV0;
        bf16* sKn = (kt & 1) ? sK0 : sK1;
        bf16* sVn = (kt & 1) ? sV0 : sV1;

        // A: all waves finished reading buf[next] (in iter kt-1); safe to overwrite
        asm volatile("s_barrier" ::: "memory");

        u64 mb[4];
        const u64* mbase = mbase0 + kt;
        if (kt + 1 < NKT) {
            const char* gk = gKbase + (size_t)(kt + 1) * 16384;
            const char* gv = gVbase + (size_t)(kt + 1) * 16384;
            #pragma unroll
            for (int i = 0; i < 4; ++i) dma16(gk + i * 4096 + tid * 16, (char*)sKn + i * 4096 + tid * 16);
            #pragma unroll
            for (int i = 0; i < 4; ++i) dma16(gv + i * 4096 + tid * 16, (char*)sVn + i * 4096 + tid * 16);
            #pragma unroll
            for (int r = 0; r < 4; ++r) mb[r] = mbase[(size_t)r * NKT];
            // 12 newer ops in flight (8 DMA next-tile + 4 mask) -> tile kt's DMA drained
            asm volatile("s_waitcnt vmcnt(12)" ::: "memory");
        } else {
            #pragma unroll
            for (int r = 0; r < 4; ++r) mb[r] = mbase[(size_t)r * NKT];
            asm volatile("s_waitcnt vmcnt(4)" ::: "memory");
        }
        // B: every wave's portion of tile kt is in LDS
        asm volatile("s_barrier" ::: "memory");

        // S = Qg @ K^T   (B-frag from swizzled sK: chunk = (kc*4+quad) ^ c)
        f32x4 sacc[4];
        #pragma unroll
        for (int nt = 0; nt < 4; ++nt)
            #pragma unroll
            for (int r = 0; r < 4; ++r) sacc[nt][r] = 0.f;

        #pragma unroll
        for (int nt = 0; nt < 4; ++nt) {
            const bf16* krow = sK + (nt * 16 + c) * 128;
            #pragma unroll
            for (int kc = 0; kc < 4; ++kc) {
                bf16x8 bfrag = *(const bf16x8*)(krow + (((kc * 4 + quad) ^ c) * 8));
                sacc[nt] = __builtin_amdgcn_mfma_f32_16x16x32_bf16(qfrag[kc], bfrag, sacc[nt], 0, 0, 0);
            }
        }

        // mask-bit + exp (scores tiny, no max needed) -> P into LDS (C->A layout xform)
        #pragma unroll
        for (int nt = 0; nt < 4; ++nt) {
            #pragma unroll
            for (int r = 0; r < 4; ++r) {
                float p = ((mb[r] >> (nt * 16 + c)) & 1ull) ? __expf(sacc[nt][r]) : 0.f;
                lsum[r] += p;
                sP[(wave * 16 + quad * 4 + r) * SP_STRIDE + nt * 16 + c] = (bf16)p;
            }
        }
        // pfrag reads only this wave's own rows -> intra-wave LDS drain suffices
        asm volatile("s_waitcnt lgkmcnt(0)" ::: "memory");

        bf16x8 pfrag[2];
        const bf16* prow = sP + (wave * 16 + c) * SP_STRIDE;
        #pragma unroll
        for (int kc = 0; kc < 2; ++kc)
            pfrag[kc] = *(const bf16x8*)(prow + kc * 32 + quad * 8);

        // O += P @ V  (B-frag from swizzled sV: chunk = (kc*4+quad) ^ (c&7))
        #pragma unroll
        for (int nt = 0; nt < 8; ++nt) {
            const bf16* vrow = sV + (nt * 16 + c) * 64;
            #pragma unroll
            for (int kc = 0; kc < 2; ++kc) {
                bf16x8 bfrag = *(const bf16x8*)(vrow + (((kc * 4 + quad) ^ (c & 7)) * 8));
                oacc[nt] = __builtin_amdgcn_mfma_f32_16x16x32_bf16(pfrag[kc], bfrag, oacc[nt], 0, 0, 0);
            }
        }
    }

    // 1 / row-sum
    #pragma unroll
    for (int r = 0; r < 4; ++r) {
        float v = lsum[r];
        v += __shfl_xor(v, 1); v += __shfl_xor(v, 2);
        v += __shfl_xor(v, 4); v += __shfl_xor(v, 8);
        lsum[r] = 1.0f / v;
    }

    __syncthreads();   // all main-phase LDS reads done; safe to repurpose buffers

    if (tid < 128)
        g_s[tid] = WV[(h * F_ + tid) * F_ + tid];

    #pragma unroll
    for (int nt = 0; nt < 8; ++nt)
        #pragma unroll
        for (int r = 0; r < 4; ++r) {
            float v = oacc[nt][r] * lsum[r];
            sOh[(wave * 16 + quad * 4 + r) * SOH_STRIDE + nt * 16 + c] = (bf16)v;
        }
    __syncthreads();

    // stage O2^T: sO2t[f][f'] = O[h*128+f'][f] * dv[f']
    #pragma unroll
    for (int i = 0; i < 16; ++i) {
        int fp4 = grp * 64 + i * 4;
        bf16x4 w;
        #pragma unroll
        for (int j = 0; j < 4; ++j) {
            int x = fp4 + j;
            w[j] = (bf16)(Om[(h * F_ + x) * F_ + fv] * g_s[x]);
        }
        *(bf16x4*)(sO2t + fv * SO2_STRIDE + fp4) = w;
    }
    __syncthreads();

    // out_partial = Oh @ O2, atomic accumulate over heads
    bf16x8 afr[4];
    const bf16* ohrow = sOh + (wave * 16 + c) * SOH_STRIDE;
    #pragma unroll
    for (int kc = 0; kc < 4; ++kc)
        afr[kc] = *(const bf16x8*)(ohrow + kc * 32 + quad * 8);

    #pragma unroll
    for (int nt = 0; nt < 8; ++nt) {
        f32x4 pacc;
        #pragma unroll
        for (int r = 0; r < 4; ++r) pacc[r] = 0.f;
        const bf16* orow = sO2t + (nt * 16 + c) * SO2_STRIDE;
        #pragma unroll
        for (int kc = 0; kc < 4; ++kc) {
            bf16x8 bfrag = *(const bf16x8*)(orow + kc * 32 + quad * 8);
            pacc = __builtin_amdgcn_mfma_f32_16x16x32_bf16(afr[kc], bfrag, pacc, 0, 0, 0);
        }
        #pragma unroll
        for (int r = 0; r < 4; ++r) {
            int qg = q0 + wave * 16 + quad * 4 + r;
            atomicAdd(out + ((size_t)(b * L_ + qg) * F_ + nt * 16 + c), pacc[r]);
        }
    }
}

extern "C" void kernel_launch(void* const* d_in, const int* in_sizes, int n_in,
                              void* d_out, int out_size, void* d_ws, size_t ws_size,
                              hipStream_t stream) {
    const float* XQ   = (const float*)d_in[0];
    const float* XK   = (const float*)d_in[1];
    const float* XV   = (const float*)d_in[2];
    const int*   mask = (const int*)d_in[3];
    const float* WQ   = (const float*)d_in[4];
    const float* WK   = (const float*)d_in[5];
    const float* WV   = (const float*)d_in[6];
    const float* Om   = (const float*)d_in[7];
    float* out = (float*)d_out;

    char* ws = (char*)d_ws;
    bf16* Kb   = (bf16*)(ws + WS_KB);
    bf16* Vtb  = (bf16*)(ws + WS_VT);
    u64*  bits = (u64*)(ws + WS_MB);

    prep_k<<<256, 256, 0, stream>>>(XK, Kb);
    prep_v<<<B_ * NKT, 256, 0, stream>>>(XV, Vtb);
    prep_mask<<<(B_ * L_ * L_) / 256, 256, 0, stream>>>(mask, bits);
    hipMemsetAsync(out, 0, (size_t)out_size * sizeof(float), stream);

    dim3 grid(L_ / QT, H_, B_);
    attn_fused_kernel<<<grid, 256, 0, stream>>>(XQ, Kb, Vtb, bits, WQ, WK, WV, Om, out);
}

// Round 4
// 166.260 us; speedup vs baseline: 1.3561x; 1.0251x over previous
//
#include <hip/hip_runtime.h>

typedef __bf16 bf16;
typedef __bf16 bf16x4 __attribute__((ext_vector_type(4)));
typedef __bf16 bf16x8 __attribute__((ext_vector_type(8)));
typedef float f32x4 __attribute__((ext_vector_type(4)));
typedef unsigned int u32;
typedef unsigned long long u64;

#define B_ 2
#define H_ 8
#define L_ 2048
#define D_ 128
#define F_ 128
#define QT 64
#define KT 64
#define NKT (L_ / KT)

// workspace layout (bytes)
#define WS_KB 0u            // Kb  : bf16 [b][k][16B-chunk swizzled], 1 MB
#define WS_VT (1u << 20)    // Vtb : bf16 tiles [b][kt][f][chunk swz], 1 MB
#define WS_MB (2u << 20)    // bits: u64 [b][q][kt], 1 MB

// LDS: sK0@0 sK1@16384 sV0@32768 sV1@49152 (16KB each, swizzled)
//      sP@65536: [64 m][72 k] bf16 = 9216 ; lws@74752: 4x64 f32 = 1024
// epilogue aliases: sOh@0 (64x136), sO2t@17408 (128x136)  (lws preserved)
#define SMEM_BYTES 75776
#define SP_OFF 65536
#define SP_STRIDE 72
#define LWS_OFF 74752
#define SOH_STRIDE 136
#define SO2_STRIDE 136

__device__ __forceinline__ void dma16(const void* g, void* l) {
    __builtin_amdgcn_global_load_lds(
        (const __attribute__((address_space(1))) u32*)g,
        (__attribute__((address_space(3))) u32*)l, 16, 0, 0);
}

// ---- fused prep: mask bitpack (blocks 0..8191), K cvt+swizzle (8192..8447),
//      V transpose+swizzle (8448..8703) ----
__global__ __launch_bounds__(256)
void prep_all(const float* __restrict__ XK, const float* __restrict__ XV,
              const int* __restrict__ mask, bf16* __restrict__ Kb,
              bf16* __restrict__ Vtb, u64* __restrict__ bits)
{
    const int bid = blockIdx.x;
    const int tid = threadIdx.x;
    if (bid < 8192) {
        // mask -> bitpacked u64; wave handles 256 elements via 4 strided ballots
        int wv = bid * 4 + (tid >> 6);
        int lane = tid & 63;
        size_t base = (size_t)wv * 256;
        #pragma unroll
        for (int s = 0; s < 4; ++s) {
            int m = mask[base + s * 64 + lane];
            u64 bal = __ballot(m != 0);
            if (lane == 0) bits[(size_t)wv * 4 + s] = bal;
        }
    } else if (bid < 8448) {
        // K -> bf16, 16B chunks XOR-swizzled within each 256B row
        int gid = (bid - 8192) * 256 + tid;       // 65536 = 4096 rows * 16 chunks
        int row = gid >> 4;
        int j   = gid & 15;
        const float* src = XK + (size_t)row * 128 + j * 8;
        float4 v0 = *(const float4*)src;
        float4 v1 = *(const float4*)(src + 4);
        bf16x8 w;
        w[0] = (bf16)v0.x; w[1] = (bf16)v0.y; w[2] = (bf16)v0.z; w[3] = (bf16)v0.w;
        w[4] = (bf16)v1.x; w[5] = (bf16)v1.y; w[6] = (bf16)v1.z; w[7] = (bf16)v1.w;
        int jp = j ^ (row & 15);
        *(bf16x8*)(Kb + (size_t)row * 128 + jp * 8) = w;
    } else {
        // V -> V^T bf16 tiles [tile][f][64k], chunk j stored at j^(f&7)
        int idx  = bid - 8448;                    // 0..255
        int tile = idx >> 2;                      // b*32 + kt
        int fq   = idx & 3;
        int f    = fq * 32 + (tid & 31);
        int j    = tid >> 5;                      // 0..7
        int bb   = tile >> 5, kt = tile & 31;
        const float* src = XV + ((size_t)(bb * L_ + kt * 64 + j * 8)) * F_ + f;
        bf16x8 w;
        #pragma unroll
        for (int jj = 0; jj < 8; ++jj) w[jj] = (bf16)src[(size_t)jj * F_];
        *(bf16x8*)(Vtb + (size_t)tile * 8192 + f * 64 + ((j ^ (f & 7)) * 8)) = w;
    }
}

// ---- main fused kernel ----
__global__ __launch_bounds__(256, 2)
void attn_fused_kernel(const float* __restrict__ XQ, const bf16* __restrict__ Kb,
                       const bf16* __restrict__ Vtb, const u64* __restrict__ bits,
                       const float* __restrict__ WQ, const float* __restrict__ WK,
                       const float* __restrict__ WV, const float* __restrict__ Om,
                       float* __restrict__ out)
{
    __shared__ __align__(16) char smem[SMEM_BYTES];
    __shared__ __align__(16) float g_s[128];

    bf16* sK0 = (bf16*)smem;
    bf16* sK1 = (bf16*)(smem + 16384);
    bf16* sV0 = (bf16*)(smem + 32768);
    bf16* sV1 = (bf16*)(smem + 49152);
    bf16* sP  = (bf16*)(smem + SP_OFF);
    float* lws = (float*)(smem + LWS_OFF);
    bf16* sOh  = (bf16*)smem;
    bf16* sO2t = (bf16*)(smem + 17408);

    const int tid  = threadIdx.x;
    const int wave = tid >> 6;
    const int lane = tid & 63;
    const int c    = lane & 15;
    const int quad = lane >> 4;
    const int qt = blockIdx.x, h = blockIdx.y, b = blockIdx.z;
    const int q0 = qt * QT;
    const int mh = wave >> 1;        // PV m-half
    const int fh = wave & 1;         // PV f-half
    const int fv  = tid & 127;       // epilogue staging
    const int grp = tid >> 7;

    if (tid < 128) {
        float wq = WQ[(h * D_ + tid) * D_ + tid];
        float wk = WK[(h * D_ + tid) * D_ + tid];
        g_s[tid] = wq * wk * 0.08838834764831845f;
    }
    __syncthreads();

    const char* gKbase = (const char*)Kb + (size_t)(b * L_) * 256;
    const char* gVbase = (const char*)Vtb + (size_t)(b * NKT) * 16384;

    // DMA tile 0
    #pragma unroll
    for (int i = 0; i < 4; ++i) dma16(gKbase + i * 4096 + tid * 16, (char*)sK0 + i * 4096 + tid * 16);
    #pragma unroll
    for (int i = 0; i < 4; ++i) dma16(gVbase + i * 4096 + tid * 16, (char*)sV0 + i * 4096 + tid * 16);

    // ALL 64 Q rows as B-fragments in registers (scaled by g, bf16): qfrag[mt][kc]
    bf16x8 qfrag[4][4];
    #pragma unroll
    for (int mt = 0; mt < 4; ++mt) {
        const float* qrow = XQ + (size_t)(b * L_ + q0 + mt * 16 + c) * D_;
        #pragma unroll
        for (int kc = 0; kc < 4; ++kc) {
            int d0 = kc * 32 + quad * 8;
            float4 v0 = *(const float4*)(qrow + d0);
            float4 v1 = *(const float4*)(qrow + d0 + 4);
            float4 g0 = *(const float4*)(g_s + d0);
            float4 g1 = *(const float4*)(g_s + d0 + 4);
            bf16x8 w;
            w[0] = (bf16)(v0.x * g0.x); w[1] = (bf16)(v0.y * g0.y);
            w[2] = (bf16)(v0.z * g0.z); w[3] = (bf16)(v0.w * g0.w);
            w[4] = (bf16)(v1.x * g1.x); w[5] = (bf16)(v1.y * g1.y);
            w[6] = (bf16)(v1.z * g1.z); w[7] = (bf16)(v1.w * g1.w);
            qfrag[mt][kc] = w;
        }
    }

    f32x4 oacc[2][4];
    #pragma unroll
    for (int mi = 0; mi < 2; ++mi)
        #pragma unroll
        for (int fi = 0; fi < 4; ++fi)
            #pragma unroll
            for (int r = 0; r < 4; ++r) oacc[mi][fi][r] = 0.f;
    float lsum[4] = {0.f, 0.f, 0.f, 0.f};

    const int shift = wave * 16 + quad * 4;

    #pragma unroll 2
    for (int kt = 0; kt < NKT; ++kt) {
        bf16* sK  = (kt & 1) ? sK1 : sK0;
        bf16* sV  = (kt & 1) ? sV1 : sV0;
        bf16* sKn = (kt & 1) ? sK0 : sK1;
        bf16* sVn = (kt & 1) ? sV0 : sV1;

        // A: all waves done reading buf[next] and done with prev iter's sP
        asm volatile("s_barrier" ::: "memory");

        // mask loads FIRST (so waiting on them later keeps next-tile DMA in flight)
        u64 mb[4];
        #pragma unroll
        for (int mt = 0; mt < 4; ++mt)
            mb[mt] = bits[(size_t)(b * L_ + q0 + mt * 16 + c) * NKT + kt];

        if (kt + 1 < NKT) {
            const char* gk = gKbase + (size_t)(kt + 1) * 16384;
            const char* gv = gVbase + (size_t)(kt + 1) * 16384;
            #pragma unroll
            for (int i = 0; i < 4; ++i) dma16(gk + i * 4096 + tid * 16, (char*)sKn + i * 4096 + tid * 16);
            #pragma unroll
            for (int i = 0; i < 4; ++i) dma16(gv + i * 4096 + tid * 16, (char*)sVn + i * 4096 + tid * 16);
            // newest 12 = 4 mask + 8 next-DMA -> tile kt's DMA drained
            asm volatile("s_waitcnt vmcnt(12)" ::: "memory");
        } else {
            asm volatile("s_waitcnt vmcnt(4)" ::: "memory");
        }
        // B: tile kt resident
        asm volatile("s_barrier" ::: "memory");

        // S^T = K @ Qg^T : wave owns k-tile = wave (A), all 4 m-tiles (B in regs)
        f32x4 tacc[4];
        #pragma unroll
        for (int mt = 0; mt < 4; ++mt)
            #pragma unroll
            for (int r = 0; r < 4; ++r) tacc[mt][r] = 0.f;

        const bf16* krow = sK + (wave * 16 + c) * 128;
        #pragma unroll
        for (int kc = 0; kc < 4; ++kc) {
            bf16x8 kfrag = *(const bf16x8*)(krow + (((kc * 4 + quad) ^ c) * 8));
            #pragma unroll
            for (int mt = 0; mt < 4; ++mt)
                tacc[mt] = __builtin_amdgcn_mfma_f32_16x16x32_bf16(kfrag, qfrag[mt][kc], tacc[mt], 0, 0, 0);
        }

        // lane (c,quad) reg r holds S[k = wave*16+quad*4+r][m = mt*16+c]
        // mask-bit + exp -> P packed along k -> single b64 write per mt
        #pragma unroll
        for (int mt = 0; mt < 4; ++mt) {
            bf16x4 pw;
            #pragma unroll
            for (int r = 0; r < 4; ++r) {
                float p = ((mb[mt] >> (shift + r)) & 1ull) ? __expf(tacc[mt][r]) : 0.f;
                lsum[mt] += p;
                pw[r] = (bf16)p;
            }
            *(bf16x4*)(sP + (mt * 16 + c) * SP_STRIDE + shift) = pw;
        }
        asm volatile("s_waitcnt lgkmcnt(0)" ::: "memory");
        // C: sP complete across waves (PV needs all k columns)
        asm volatile("s_barrier" ::: "memory");

        // O += P @ V : 2x2 wave split (m-half mh, f-half fh)
        #pragma unroll
        for (int kc = 0; kc < 2; ++kc) {
            bf16x8 pfrag[2];
            #pragma unroll
            for (int mi = 0; mi < 2; ++mi)
                pfrag[mi] = *(const bf16x8*)(sP + ((2 * mh + mi) * 16 + c) * SP_STRIDE + kc * 32 + quad * 8);
            #pragma unroll
            for (int fi = 0; fi < 4; ++fi) {
                const bf16* vrow = sV + ((fh * 4 + fi) * 16 + c) * 64;
                bf16x8 vfrag = *(const bf16x8*)(vrow + (((kc * 4 + quad) ^ (c & 7)) * 8));
                #pragma unroll
                for (int mi = 0; mi < 2; ++mi)
                    oacc[mi][fi] = __builtin_amdgcn_mfma_f32_16x16x32_bf16(pfrag[mi], vfrag, oacc[mi][fi], 0, 0, 0);
            }
        }
    }

    // per-wave partial row sums: reduce over quad (k-subranges), publish to LDS
    #pragma unroll
    for (int mt = 0; mt < 4; ++mt) {
        float v = lsum[mt];
        v += __shfl_xor(v, 16); v += __shfl_xor(v, 32);
        if (lane < 16) lws[wave * 64 + mt * 16 + lane] = v;
    }
    __syncthreads();   // main-phase LDS reads done + lws visible

    if (tid < 128)
        g_s[tid] = WV[(h * F_ + tid) * F_ + tid];

    // linv per oacc row, then normalized Oh -> sOh
    float linv[2][4];
    #pragma unroll
    for (int mi = 0; mi < 2; ++mi)
        #pragma unroll
        for (int r = 0; r < 4; ++r) {
            int q_local = (2 * mh + mi) * 16 + quad * 4 + r;
            float s = lws[q_local] + lws[64 + q_local] + lws[128 + q_local] + lws[192 + q_local];
            linv[mi][r] = 1.0f / s;
        }
    #pragma unroll
    for (int mi = 0; mi < 2; ++mi)
        #pragma unroll
        for (int fi = 0; fi < 4; ++fi)
            #pragma unroll
            for (int r = 0; r < 4; ++r) {
                int q_local = (2 * mh + mi) * 16 + quad * 4 + r;
                int f_col   = (fh * 4 + fi) * 16 + c;
                sOh[q_local * SOH_STRIDE + f_col] = (bf16)(oacc[mi][fi][r] * linv[mi][r]);
            }
    __syncthreads();

    // stage O2^T: sO2t[f][f'] = O[h*128+f'][f] * dv[f']
    #pragma unroll
    for (int i = 0; i < 16; ++i) {
        int fp4 = grp * 64 + i * 4;
        bf16x4 w;
        #pragma unroll
        for (int j = 0; j < 4; ++j) {
            int x = fp4 + j;
            w[j] = (bf16)(Om[(h * F_ + x) * F_ + fv] * g_s[x]);
        }
        *(bf16x4*)(sO2t + fv * SO2_STRIDE + fp4) = w;
    }
    __syncthreads();

    // out_partial = Oh @ O2, atomic accumulate over heads
    bf16x8 afr[4];
    const bf16* ohrow = sOh + (wave * 16 + c) * SOH_STRIDE;
    #pragma unroll
    for (int kc = 0; kc < 4; ++kc)
        afr[kc] = *(const bf16x8*)(ohrow + kc * 32 + quad * 8);

    #pragma unroll
    for (int nt = 0; nt < 8; ++nt) {
        f32x4 pacc;
        #pragma unroll
        for (int r = 0; r < 4; ++r) pacc[r] = 0.f;
        const bf16* orow = sO2t + (nt * 16 + c) * SO2_STRIDE;
        #pragma unroll
        for (int kc = 0; kc < 4; ++kc) {
            bf16x8 bfrag = *(const bf16x8*)(orow + kc * 32 + quad * 8);
            pacc = __builtin_amdgcn_mfma_f32_16x16x32_bf16(afr[kc], bfrag, pacc, 0, 0, 0);
        }
        #pragma unroll
        for (int r = 0; r < 4; ++r) {
            int qg = q0 + wave * 16 + quad * 4 + r;
            atomicAdd(out + ((size_t)(b * L_ + qg) * F_ + nt * 16 + c), pacc[r]);
        }
    }
}

extern "C" void kernel_launch(void* const* d_in, const int* in_sizes, int n_in,
                              void* d_out, int out_size, void* d_ws, size_t ws_size,
                              hipStream_t stream) {
    const float* XQ   = (const float*)d_in[0];
    const float* XK   = (const float*)d_in[1];
    const float* XV   = (const float*)d_in[2];
    const int*   mask = (const int*)d_in[3];
    const float* WQ   = (const float*)d_in[4];
    const float* WK   = (const float*)d_in[5];
    const float* WV   = (const float*)d_in[6];
    const float* Om   = (const float*)d_in[7];
    float* out = (float*)d_out;

    char* ws = (char*)d_ws;
    bf16* Kb   = (bf16*)(ws + WS_KB);
    bf16* Vtb  = (bf16*)(ws + WS_VT);
    u64*  bits = (u64*)(ws + WS_MB);

    prep_all<<<8704, 256, 0, stream>>>(XK, XV, mask, Kb, Vtb, bits);
    hipMemsetAsync(out, 0, (size_t)out_size * sizeof(float), stream);

    dim3 grid(L_ / QT, H_, B_);
    attn_fused_kernel<<<grid, 256, 0, stream>>>(XQ, Kb, Vtb, bits, WQ, WK, WV, Om, out);
}

// Round 5
// 165.465 us; speedup vs baseline: 1.3626x; 1.0048x over previous
//
#include <hip/hip_runtime.h>

typedef __bf16 bf16;
typedef __bf16 bf16x4 __attribute__((ext_vector_type(4)));
typedef __bf16 bf16x8 __attribute__((ext_vector_type(8)));
typedef float f32x4 __attribute__((ext_vector_type(4)));
typedef unsigned int u32;
typedef unsigned long long u64;

#define B_ 2
#define H_ 8
#define L_ 2048
#define D_ 128
#define F_ 128
#define QT 64
#define KT 64
#define NKT (L_ / KT)

// workspace layout (bytes)
#define WS_KB 0u            // Kb  : bf16 [b][k][16B-chunk swizzled], 1 MB
#define WS_VT (1u << 20)    // Vtb : bf16 tiles [b][kt][f][chunk swz], 1 MB
#define WS_MB (2u << 20)    // bits: u64 [b][q][kt], 1 MB

// LDS: sK0@0 sK1@16384 sV0@32768 sV1@49152 (16KB each, swizzled)
//      sP@65536: [64 m][72 k] bf16 = 9216 ; lws@74752: 8x32 f32 = 1024
// epilogue aliases: sOh@0 (64x136), sO2t@17408 (128x136)  (lws preserved)
// 75776 + g_s(512) ~ 76.3 KB -> 2 blocks/CU @ 8 waves = 16 waves/CU
#define SMEM_BYTES 75776
#define SP_OFF 65536
#define SP_STRIDE 72
#define LWS_OFF 74752
#define SOH_STRIDE 136
#define SO2_STRIDE 136

__device__ __forceinline__ void dma16(const void* g, void* l) {
    __builtin_amdgcn_global_load_lds(
        (const __attribute__((address_space(1))) u32*)g,
        (__attribute__((address_space(3))) u32*)l, 16, 0, 0);
}

// ---- fused prep: mask bitpack (blocks 0..8191), K cvt+swizzle (8192..8447),
//      V transpose+swizzle (8448..8703) ----
__global__ __launch_bounds__(256)
void prep_all(const float* __restrict__ XK, const float* __restrict__ XV,
              const int* __restrict__ mask, bf16* __restrict__ Kb,
              bf16* __restrict__ Vtb, u64* __restrict__ bits)
{
    const int bid = blockIdx.x;
    const int tid = threadIdx.x;
    if (bid < 8192) {
        int wv = bid * 4 + (tid >> 6);
        int lane = tid & 63;
        size_t base = (size_t)wv * 256;
        #pragma unroll
        for (int s = 0; s < 4; ++s) {
            int m = mask[base + s * 64 + lane];
            u64 bal = __ballot(m != 0);
            if (lane == 0) bits[(size_t)wv * 4 + s] = bal;
        }
    } else if (bid < 8448) {
        int gid = (bid - 8192) * 256 + tid;
        int row = gid >> 4;
        int j   = gid & 15;
        const float* src = XK + (size_t)row * 128 + j * 8;
        float4 v0 = *(const float4*)src;
        float4 v1 = *(const float4*)(src + 4);
        bf16x8 w;
        w[0] = (bf16)v0.x; w[1] = (bf16)v0.y; w[2] = (bf16)v0.z; w[3] = (bf16)v0.w;
        w[4] = (bf16)v1.x; w[5] = (bf16)v1.y; w[6] = (bf16)v1.z; w[7] = (bf16)v1.w;
        int jp = j ^ (row & 15);
        *(bf16x8*)(Kb + (size_t)row * 128 + jp * 8) = w;
    } else {
        int idx  = bid - 8448;
        int tile = idx >> 2;
        int fq   = idx & 3;
        int f    = fq * 32 + (tid & 31);
        int j    = tid >> 5;
        int bb   = tile >> 5, kt = tile & 31;
        const float* src = XV + ((size_t)(bb * L_ + kt * 64 + j * 8)) * F_ + f;
        bf16x8 w;
        #pragma unroll
        for (int jj = 0; jj < 8; ++jj) w[jj] = (bf16)src[(size_t)jj * F_];
        *(bf16x8*)(Vtb + (size_t)tile * 8192 + f * 64 + ((j ^ (f & 7)) * 8)) = w;
    }
}

// ---- main fused kernel: 512 threads / 8 waves per block ----
__global__ __launch_bounds__(512, 4)
void attn_fused_kernel(const float* __restrict__ XQ, const bf16* __restrict__ Kb,
                       const bf16* __restrict__ Vtb, const u64* __restrict__ bits,
                       const float* __restrict__ WQ, const float* __restrict__ WK,
                       const float* __restrict__ WV, const float* __restrict__ Om,
                       float* __restrict__ out)
{
    __shared__ __align__(16) char smem[SMEM_BYTES];
    __shared__ __align__(16) float g_s[128];

    bf16* sK0 = (bf16*)smem;
    bf16* sK1 = (bf16*)(smem + 16384);
    bf16* sV0 = (bf16*)(smem + 32768);
    bf16* sV1 = (bf16*)(smem + 49152);
    bf16* sP  = (bf16*)(smem + SP_OFF);
    float* lws = (float*)(smem + LWS_OFF);
    bf16* sOh  = (bf16*)smem;
    bf16* sO2t = (bf16*)(smem + 17408);

    const int tid  = threadIdx.x;
    const int wave = tid >> 6;        // 0..7
    const int lane = tid & 63;
    const int c    = lane & 15;
    const int quad = lane >> 4;
    const int qt = blockIdx.x, h = blockIdx.y, b = blockIdx.z;
    const int q0 = qt * QT;

    // S-phase role: k-tile kq, m-half msel (m-tiles msel*2+{0,1})
    const int kq   = wave & 3;
    const int msel = wave >> 2;
    // PV role: m-tile mq, f-half fh
    const int mq = wave & 3;
    const int fh = wave >> 2;
    // epilogue staging
    const int fv  = tid & 127;
    const int grp = tid >> 7;         // 0..3

    if (tid < 128) {
        float wq = WQ[(h * D_ + tid) * D_ + tid];
        float wk = WK[(h * D_ + tid) * D_ + tid];
        g_s[tid] = wq * wk * 0.08838834764831845f;
    }
    __syncthreads();

    const char* gKbase = (const char*)Kb + (size_t)(b * L_) * 256;
    const char* gVbase = (const char*)Vtb + (size_t)(b * NKT) * 16384;

    // DMA tile 0 (512 threads x 16B x 2 = 16 KB per array)
    #pragma unroll
    for (int i = 0; i < 2; ++i) dma16(gKbase + i * 8192 + tid * 16, (char*)sK0 + i * 8192 + tid * 16);
    #pragma unroll
    for (int i = 0; i < 2; ++i) dma16(gVbase + i * 8192 + tid * 16, (char*)sV0 + i * 8192 + tid * 16);

    // This wave's 2 Q m-tiles as B-fragments in registers (scaled by g, bf16)
    bf16x8 qfrag[2][4];
    #pragma unroll
    for (int mi = 0; mi < 2; ++mi) {
        const float* qrow = XQ + (size_t)(b * L_ + q0 + (msel * 2 + mi) * 16 + c) * D_;
        #pragma unroll
        for (int kc = 0; kc < 4; ++kc) {
            int d0 = kc * 32 + quad * 8;
            float4 v0 = *(const float4*)(qrow + d0);
            float4 v1 = *(const float4*)(qrow + d0 + 4);
            float4 g0 = *(const float4*)(g_s + d0);
            float4 g1 = *(const float4*)(g_s + d0 + 4);
            bf16x8 w;
            w[0] = (bf16)(v0.x * g0.x); w[1] = (bf16)(v0.y * g0.y);
            w[2] = (bf16)(v0.z * g0.z); w[3] = (bf16)(v0.w * g0.w);
            w[4] = (bf16)(v1.x * g1.x); w[5] = (bf16)(v1.y * g1.y);
            w[6] = (bf16)(v1.z * g1.z); w[7] = (bf16)(v1.w * g1.w);
            qfrag[mi][kc] = w;
        }
    }

    f32x4 oacc[4];
    #pragma unroll
    for (int fi = 0; fi < 4; ++fi)
        #pragma unroll
        for (int r = 0; r < 4; ++r) oacc[fi][r] = 0.f;
    float lsum[2] = {0.f, 0.f};

    const int shift = kq * 16 + quad * 4;

    #pragma unroll 2
    for (int kt = 0; kt < NKT; ++kt) {
        bf16* sK  = (kt & 1) ? sK1 : sK0;
        bf16* sV  = (kt & 1) ? sV1 : sV0;
        bf16* sKn = (kt & 1) ? sK0 : sK1;
        bf16* sVn = (kt & 1) ? sV0 : sV1;

        // A: all waves done reading buf[next] and prev iter's sP
        asm volatile("s_barrier" ::: "memory");

        // mask loads first (stay in flight across the drain below)
        u64 mb[2];
        #pragma unroll
        for (int mi = 0; mi < 2; ++mi)
            mb[mi] = bits[(size_t)(b * L_ + q0 + (msel * 2 + mi) * 16 + c) * NKT + kt];

        if (kt + 1 < NKT) {
            const char* gk = gKbase + (size_t)(kt + 1) * 16384;
            const char* gv = gVbase + (size_t)(kt + 1) * 16384;
            #pragma unroll
            for (int i = 0; i < 2; ++i) dma16(gk + i * 8192 + tid * 16, (char*)sKn + i * 8192 + tid * 16);
            #pragma unroll
            for (int i = 0; i < 2; ++i) dma16(gv + i * 8192 + tid * 16, (char*)sVn + i * 8192 + tid * 16);
            // newest 6 = 2 mask + 4 next-DMA -> tile kt's 4 DMA drained
            asm volatile("s_waitcnt vmcnt(6)" ::: "memory");
        } else {
            asm volatile("s_waitcnt vmcnt(2)" ::: "memory");
        }
        // B: tile kt resident
        asm volatile("s_barrier" ::: "memory");

        // S^T = K @ Qg^T : wave's k-tile kq (A from LDS), 2 m-tiles (B in regs)
        f32x4 tacc[2];
        #pragma unroll
        for (int mi = 0; mi < 2; ++mi)
            #pragma unroll
            for (int r = 0; r < 4; ++r) tacc[mi][r] = 0.f;

        const bf16* krow = sK + (kq * 16 + c) * 128;
        #pragma unroll
        for (int kc = 0; kc < 4; ++kc) {
            bf16x8 kfrag = *(const bf16x8*)(krow + (((kc * 4 + quad) ^ c) * 8));
            #pragma unroll
            for (int mi = 0; mi < 2; ++mi)
                tacc[mi] = __builtin_amdgcn_mfma_f32_16x16x32_bf16(kfrag, qfrag[mi][kc], tacc[mi], 0, 0, 0);
        }

        // lane(c,quad) reg r = S^T[k=kq*16+quad*4+r][m=(msel*2+mi)*16+c]
        #pragma unroll
        for (int mi = 0; mi < 2; ++mi) {
            bf16x4 pw;
            #pragma unroll
            for (int r = 0; r < 4; ++r) {
                float p = ((mb[mi] >> (shift + r)) & 1ull) ? __expf(tacc[mi][r]) : 0.f;
                lsum[mi] += p;
                pw[r] = (bf16)p;
            }
            *(bf16x4*)(sP + ((msel * 2 + mi) * 16 + c) * SP_STRIDE + shift) = pw;
        }
        asm volatile("s_waitcnt lgkmcnt(0)" ::: "memory");
        // C: sP complete across waves
        asm volatile("s_barrier" ::: "memory");

        // O += P @ V : wave (mq, fh)
        #pragma unroll
        for (int kc = 0; kc < 2; ++kc) {
            bf16x8 pfrag = *(const bf16x8*)(sP + (mq * 16 + c) * SP_STRIDE + kc * 32 + quad * 8);
            #pragma unroll
            for (int fi = 0; fi < 4; ++fi) {
                const bf16* vrow = sV + ((fh * 4 + fi) * 16 + c) * 64;
                bf16x8 vfrag = *(const bf16x8*)(vrow + (((kc * 4 + quad) ^ (c & 7)) * 8));
                oacc[fi] = __builtin_amdgcn_mfma_f32_16x16x32_bf16(pfrag, vfrag, oacc[fi], 0, 0, 0);
            }
        }
    }

    // per-wave partial row sums (this wave covered 16 k of each of its 2 m-tiles)
    #pragma unroll
    for (int mi = 0; mi < 2; ++mi) {
        float v = lsum[mi];
        v += __shfl_xor(v, 16); v += __shfl_xor(v, 32);
        if (lane < 16) lws[wave * 32 + mi * 16 + lane] = v;
    }
    __syncthreads();   // main-phase LDS reads done + lws visible

    if (tid < 128)
        g_s[tid] = WV[(h * F_ + tid) * F_ + tid];

    // linv for this wave's PV rows (m-tile mq): sum the 4 k-tile partials
    float linv[4];
    #pragma unroll
    for (int r = 0; r < 4; ++r) {
        int cc = quad * 4 + r;
        int base = (mq >> 1) * 4;           // waves covering this m-half
        int off  = (mq & 1) * 16 + cc;
        float s = lws[(base + 0) * 32 + off] + lws[(base + 1) * 32 + off]
                + lws[(base + 2) * 32 + off] + lws[(base + 3) * 32 + off];
        linv[r] = 1.0f / s;
    }
    #pragma unroll
    for (int fi = 0; fi < 4; ++fi)
        #pragma unroll
        for (int r = 0; r < 4; ++r) {
            int q_local = mq * 16 + quad * 4 + r;
            int f_col   = (fh * 4 + fi) * 16 + c;
            sOh[q_local * SOH_STRIDE + f_col] = (bf16)(oacc[fi][r] * linv[r]);
        }
    __syncthreads();

    // stage O2^T: sO2t[f][f'] = O[h*128+f'][f] * dv[f']   (512 threads)
    #pragma unroll
    for (int i = 0; i < 8; ++i) {
        int fp4 = grp * 32 + i * 4;
        bf16x4 w;
        #pragma unroll
        for (int j = 0; j < 4; ++j) {
            int x = fp4 + j;
            w[j] = (bf16)(Om[(h * F_ + x) * F_ + fv] * g_s[x]);
        }
        *(bf16x4*)(sO2t + fv * SO2_STRIDE + fp4) = w;
    }
    __syncthreads();

    // out_partial = Oh @ O2 : wave (pm = m-tile, pf = f-half)
    const int pm = wave & 3;
    const int pf = wave >> 2;
    bf16x8 afr[4];
    const bf16* ohrow = sOh + (pm * 16 + c) * SOH_STRIDE;
    #pragma unroll
    for (int kc = 0; kc < 4; ++kc)
        afr[kc] = *(const bf16x8*)(ohrow + kc * 32 + quad * 8);

    #pragma unroll
    for (int nt = 0; nt < 4; ++nt) {
        f32x4 pacc;
        #pragma unroll
        for (int r = 0; r < 4; ++r) pacc[r] = 0.f;
        const bf16* orow = sO2t + ((pf * 4 + nt) * 16 + c) * SO2_STRIDE;
        #pragma unroll
        for (int kc = 0; kc < 4; ++kc) {
            bf16x8 bfrag = *(const bf16x8*)(orow + kc * 32 + quad * 8);
            pacc = __builtin_amdgcn_mfma_f32_16x16x32_bf16(afr[kc], bfrag, pacc, 0, 0, 0);
        }
        #pragma unroll
        for (int r = 0; r < 4; ++r) {
            int qg = q0 + pm * 16 + quad * 4 + r;
            atomicAdd(out + ((size_t)(b * L_ + qg) * F_ + (pf * 4 + nt) * 16 + c), pacc[r]);
        }
    }
}

extern "C" void kernel_launch(void* const* d_in, const int* in_sizes, int n_in,
                              void* d_out, int out_size, void* d_ws, size_t ws_size,
                              hipStream_t stream) {
    const float* XQ   = (const float*)d_in[0];
    const float* XK   = (const float*)d_in[1];
    const float* XV   = (const float*)d_in[2];
    const int*   mask = (const int*)d_in[3];
    const float* WQ   = (const float*)d_in[4];
    const float* WK   = (const float*)d_in[5];
    const float* WV   = (const float*)d_in[6];
    const float* Om   = (const float*)d_in[7];
    float* out = (float*)d_out;

    char* ws = (char*)d_ws;
    bf16* Kb   = (bf16*)(ws + WS_KB);
    bf16* Vtb  = (bf16*)(ws + WS_VT);
    u64*  bits = (u64*)(ws + WS_MB);

    prep_all<<<8704, 256, 0, stream>>>(XK, XV, mask, Kb, Vtb, bits);
    hipMemsetAsync(out, 0, (size_t)out_size * sizeof(float), stream);

    dim3 grid(L_ / QT, H_, B_);
    attn_fused_kernel<<<grid, 512, 0, stream>>>(XQ, Kb, Vtb, bits, WQ, WK, WV, Om, out);
}

// Round 6
// 156.031 us; speedup vs baseline: 1.4450x; 1.0605x over previous
//
#include <hip/hip_runtime.h>

typedef __bf16 bf16;
typedef __bf16 bf16x4 __attribute__((ext_vector_type(4)));
typedef __bf16 bf16x8 __attribute__((ext_vector_type(8)));
typedef float f32x4 __attribute__((ext_vector_type(4)));
typedef short s16x4 __attribute__((ext_vector_type(4)));
typedef unsigned int u32;
typedef unsigned long long u64;

#define B_ 2
#define H_ 8
#define L_ 2048
#define D_ 128
#define F_ 128
#define QT 64
#define KT 64
#define NKT (L_ / KT)

// workspace layout (bytes)
#define WS_KB 0u            // Kb  : bf16 [b][k][16B-chunk swizzled], 1 MB
#define WS_VT (1u << 20)    // Vtb : bf16 tiles [b][kt][f][8B-group swz], 1 MB
#define WS_MB (2u << 20)    // bits: u64 [b][q][kt], 1 MB

// LDS main: sK0@0 sK1@16384 sV0@32768 sV1@49152 (16KB each), lws@65536 (512B)
// epilogue: pOx@0 f32 [64][132] = 33792 ; sOh@36864 bf16 [64][136] = 17408 ;
//           sO2t@0 bf16 [128][136] = 34816 (after pOx reads done) ; lws kept.
#define SMEM_BYTES 66048
#define LWS_OFF 65536
#define POX_STRIDE 132
#define SOH_OFF 36864
#define SOH_STRIDE 136
#define SO2_STRIDE 136

__device__ __forceinline__ void dma16(const void* g, void* l) {
    __builtin_amdgcn_global_load_lds(
        (const __attribute__((address_space(1))) u32*)g,
        (__attribute__((address_space(3))) u32*)l, 16, 0, 0);
}

__device__ __forceinline__ f32x4 mfma32(bf16x8 a, bf16x8 b, f32x4 c) {
    return __builtin_amdgcn_mfma_f32_16x16x32_bf16(a, b, c, 0, 0, 0);
}

__device__ __forceinline__ f32x4 mfma16(bf16x4 a, bf16x4 b, f32x4 c) {
#if __has_builtin(__builtin_amdgcn_mfma_f32_16x16x16_bf16)
    return __builtin_amdgcn_mfma_f32_16x16x16_bf16(a, b, c, 0, 0, 0);
#else
    s16x4 as = __builtin_bit_cast(s16x4, a);
    s16x4 bs = __builtin_bit_cast(s16x4, b);
    return __builtin_amdgcn_mfma_f32_16x16x16bf16_1k(as, bs, c, 0, 0, 0);
#endif
}

// ---- fused prep: mask bitpack (0..8191), K cvt+swz (8192..8447), V^T (8448..8703)
__global__ __launch_bounds__(256)
void prep_all(const float* __restrict__ XK, const float* __restrict__ XV,
              const int* __restrict__ mask, bf16* __restrict__ Kb,
              bf16* __restrict__ Vtb, u64* __restrict__ bits)
{
    const int bid = blockIdx.x;
    const int tid = threadIdx.x;
    if (bid < 8192) {
        int wv = bid * 4 + (tid >> 6);
        int lane = tid & 63;
        size_t base = (size_t)wv * 256;
        #pragma unroll
        for (int s = 0; s < 4; ++s) {
            int m = mask[base + s * 64 + lane];
            u64 bal = __ballot(m != 0);
            if (lane == 0) bits[(size_t)wv * 4 + s] = bal;
        }
    } else if (bid < 8448) {
        int gid = (bid - 8192) * 256 + tid;
        int row = gid >> 4;
        int j   = gid & 15;
        const float* src = XK + (size_t)row * 128 + j * 8;
        float4 v0 = *(const float4*)src;
        float4 v1 = *(const float4*)(src + 4);
        bf16x8 w;
        w[0] = (bf16)v0.x; w[1] = (bf16)v0.y; w[2] = (bf16)v0.z; w[3] = (bf16)v0.w;
        w[4] = (bf16)v1.x; w[5] = (bf16)v1.y; w[6] = (bf16)v1.z; w[7] = (bf16)v1.w;
        int jp = j ^ (row & 15);
        *(bf16x8*)(Kb + (size_t)row * 128 + jp * 8) = w;
    } else {
        // V^T tiles [tile][f][64k]; 8B group g (k=4g..4g+3) stored at g^(f&15)
        int idx  = bid - 8448;
        int tile = idx >> 2;
        int fq   = idx & 3;
        int f    = fq * 32 + (tid & 31);
        int j    = tid >> 5;                  // 0..7 -> k = 8j..8j+7
        int bb   = tile >> 5, kt = tile & 31;
        const float* src = XV + ((size_t)(bb * L_ + kt * 64 + j * 8)) * F_ + f;
        bf16x4 w0, w1;
        #pragma unroll
        for (int jj = 0; jj < 4; ++jj) {
            w0[jj] = (bf16)src[(size_t)jj * F_];
            w1[jj] = (bf16)src[(size_t)(4 + jj) * F_];
        }
        bf16* outp = Vtb + (size_t)tile * 8192 + f * 64;
        *(bf16x4*)(outp + (((2 * j) ^ (f & 15)) * 4)) = w0;
        *(bf16x4*)(outp + (((2 * j + 1) ^ (f & 15)) * 4)) = w1;
    }
}

// ---- main fused kernel: 512 threads / 8 waves; wave = (kh, msel) ----
__global__ __launch_bounds__(512, 4)
void attn_fused_kernel(const float* __restrict__ XQ, const bf16* __restrict__ Kb,
                       const bf16* __restrict__ Vtb, const u64* __restrict__ bits,
                       const float* __restrict__ WQ, const float* __restrict__ WK,
                       const float* __restrict__ WV, const float* __restrict__ Om,
                       float* __restrict__ out)
{
    __shared__ __align__(16) char smem[SMEM_BYTES];
    __shared__ __align__(16) float g_s[128];

    bf16* sK0 = (bf16*)smem;
    bf16* sK1 = (bf16*)(smem + 16384);
    bf16* sV0 = (bf16*)(smem + 32768);
    bf16* sV1 = (bf16*)(smem + 49152);
    float* lws = (float*)(smem + LWS_OFF);
    float* pOx = (float*)smem;                 // epilogue
    bf16* sOh  = (bf16*)(smem + SOH_OFF);      // epilogue
    bf16* sO2t = (bf16*)smem;                  // epilogue (after pOx done)

    const int tid  = threadIdx.x;
    const int wave = tid >> 6;        // 0..7
    const int lane = tid & 63;
    const int c    = lane & 15;
    const int quad = lane >> 4;
    const int qt = blockIdx.x, h = blockIdx.y, b = blockIdx.z;
    const int q0 = qt * QT;

    const int kh   = wave >> 2;       // k-half (32 k)
    const int msel = wave & 3;        // m-tile (16 m)
    const int fv  = tid & 127;        // epilogue staging
    const int grp = tid >> 7;         // 0..3

    if (tid < 128) {
        float wq = WQ[(h * D_ + tid) * D_ + tid];
        float wk = WK[(h * D_ + tid) * D_ + tid];
        g_s[tid] = wq * wk * 0.08838834764831845f;
    }
    __syncthreads();

    const char* gKbase = (const char*)Kb + (size_t)(b * L_) * 256;
    const char* gVbase = (const char*)Vtb + (size_t)(b * NKT) * 16384;

    // DMA tile 0
    #pragma unroll
    for (int i = 0; i < 2; ++i) dma16(gKbase + i * 8192 + tid * 16, (char*)sK0 + i * 8192 + tid * 16);
    #pragma unroll
    for (int i = 0; i < 2; ++i) dma16(gVbase + i * 8192 + tid * 16, (char*)sV0 + i * 8192 + tid * 16);

    // wave's Q m-tile as B-fragments (scaled by g, bf16), loop-invariant
    bf16x8 qfrag[4];
    {
        const float* qrow = XQ + (size_t)(b * L_ + q0 + msel * 16 + c) * D_;
        #pragma unroll
        for (int kc = 0; kc < 4; ++kc) {
            int d0 = kc * 32 + quad * 8;
            float4 v0 = *(const float4*)(qrow + d0);
            float4 v1 = *(const float4*)(qrow + d0 + 4);
            float4 g0 = *(const float4*)(g_s + d0);
            float4 g1 = *(const float4*)(g_s + d0 + 4);
            bf16x8 w;
            w[0] = (bf16)(v0.x * g0.x); w[1] = (bf16)(v0.y * g0.y);
            w[2] = (bf16)(v0.z * g0.z); w[3] = (bf16)(v0.w * g0.w);
            w[4] = (bf16)(v1.x * g1.x); w[5] = (bf16)(v1.y * g1.y);
            w[6] = (bf16)(v1.z * g1.z); w[7] = (bf16)(v1.w * g1.w);
            qfrag[kc] = w;
        }
    }

    f32x4 oacc[8];                     // partial O[m-tile msel][128 f] for kh's 32 k
    #pragma unroll
    for (int fi = 0; fi < 8; ++fi)
        #pragma unroll
        for (int r = 0; r < 4; ++r) oacc[fi][r] = 0.f;
    float lsum = 0.f;                  // per-lane: row m = msel*16+c, wave's k slice

    const u64* mrow = bits + (size_t)(b * L_ + q0 + msel * 16 + c) * NKT;

    #pragma unroll 2
    for (int kt = 0; kt < NKT; ++kt) {
        bf16* sK  = (kt & 1) ? sK1 : sK0;
        bf16* sV  = (kt & 1) ? sV1 : sV0;
        bf16* sKn = (kt & 1) ? sK0 : sK1;
        bf16* sVn = (kt & 1) ? sV0 : sV1;

        // A: all waves done reading buf[next]
        asm volatile("s_barrier" ::: "memory");

        u64 mb = mrow[kt];

        if (kt + 1 < NKT) {
            const char* gk = gKbase + (size_t)(kt + 1) * 16384;
            const char* gv = gVbase + (size_t)(kt + 1) * 16384;
            #pragma unroll
            for (int i = 0; i < 2; ++i) dma16(gk + i * 8192 + tid * 16, (char*)sKn + i * 8192 + tid * 16);
            #pragma unroll
            for (int i = 0; i < 2; ++i) dma16(gv + i * 8192 + tid * 16, (char*)sVn + i * 8192 + tid * 16);
            // newest 5 = 1 mask + 4 next-DMA -> tile kt's DMA drained
            asm volatile("s_waitcnt vmcnt(5)" ::: "memory");
        } else {
            asm volatile("s_waitcnt vmcnt(1)" ::: "memory");
        }
        // B: tile kt resident
        asm volatile("s_barrier" ::: "memory");

        // S^T = K @ Qg^T for wave's 2 k-tiles (kh*2+kti)
        f32x4 tacc[2];
        #pragma unroll
        for (int kti = 0; kti < 2; ++kti)
            #pragma unroll
            for (int r = 0; r < 4; ++r) tacc[kti][r] = 0.f;

        #pragma unroll
        for (int kti = 0; kti < 2; ++kti) {
            const bf16* krow = sK + ((kh * 2 + kti) * 16 + c) * 128;
            #pragma unroll
            for (int kc = 0; kc < 4; ++kc) {
                bf16x8 kfrag = *(const bf16x8*)(krow + (((kc * 4 + quad) ^ c) * 8));
                tacc[kti] = mfma32(kfrag, qfrag[kc], tacc[kti]);
            }
        }

        // lane(c,quad) reg r = S^T[k = kh*32+kti*16+quad*4+r][m = msel*16+c]
        // -> exp -> DIRECTLY the A-operand of 16x16x16 MFMA (m=lane&15, k=quad*4+j)
        bf16x4 pfrag[2];
        #pragma unroll
        for (int kti = 0; kti < 2; ++kti) {
            #pragma unroll
            for (int r = 0; r < 4; ++r) {
                float p = ((mb >> (kh * 32 + kti * 16 + quad * 4 + r)) & 1ull)
                          ? __expf(tacc[kti][r]) : 0.f;
                lsum += p;
                pfrag[kti][r] = (bf16)p;
            }
        }

        // O_partial += P @ V over wave's 32 k (no LDS round trip, no 3rd barrier)
        #pragma unroll
        for (int fi = 0; fi < 8; ++fi) {
            #pragma unroll
            for (int kti = 0; kti < 2; ++kti) {
                int g = kh * 8 + kti * 4 + quad;
                bf16x4 vfrag = *(const bf16x4*)(sV + (fi * 16 + c) * 64 + ((g ^ c) * 4));
                oacc[fi] = mfma16(pfrag[kti], vfrag, oacc[fi]);
            }
        }
    }

    // publish per-wave row sums: lane c holds sum over wave's 32k after quad-reduce
    {
        float v = lsum;
        v += __shfl_xor(v, 16); v += __shfl_xor(v, 32);
        if (lane < 16) lws[wave * 16 + lane] = v;
    }
    if (tid < 128)
        g_s[tid] = WV[(h * F_ + tid) * F_ + tid];   // dv (g_s no longer needed)
    __syncthreads();   // main-loop LDS reads done; lws visible

    // kh=1 waves dump partial O to pOx
    if (kh == 1) {
        #pragma unroll
        for (int fi = 0; fi < 8; ++fi)
            #pragma unroll
            for (int r = 0; r < 4; ++r)
                pOx[(msel * 16 + quad * 4 + r) * POX_STRIDE + fi * 16 + c] = oacc[fi][r];
    }
    __syncthreads();

    // kh=0 waves: combine halves, normalize, write sOh (bf16)
    if (kh == 0) {
        float linv[4];
        #pragma unroll
        for (int r = 0; r < 4; ++r) {
            int m16 = quad * 4 + r;
            linv[r] = 1.0f / (lws[msel * 16 + m16] + lws[(4 + msel) * 16 + m16]);
        }
        #pragma unroll
        for (int fi = 0; fi < 8; ++fi)
            #pragma unroll
            for (int r = 0; r < 4; ++r) {
                int row = msel * 16 + quad * 4 + r;
                float v = (oacc[fi][r] + pOx[row * POX_STRIDE + fi * 16 + c]) * linv[r];
                sOh[row * SOH_STRIDE + fi * 16 + c] = (bf16)v;
            }
    }
    __syncthreads();

    // stage O2^T: sO2t[f][f'] = O[h*128+f'][f] * dv[f']  (reuses pOx region)
    #pragma unroll
    for (int i = 0; i < 8; ++i) {
        int fp4 = grp * 32 + i * 4;
        bf16x4 w;
        #pragma unroll
        for (int j = 0; j < 4; ++j) {
            int x = fp4 + j;
            w[j] = (bf16)(Om[(h * F_ + x) * F_ + fv] * g_s[x]);
        }
        *(bf16x4*)(sO2t + fv * SO2_STRIDE + fp4) = w;
    }
    __syncthreads();

    // out_partial = Oh @ O2 : wave (pm = m-tile, pf = f-half)
    const int pm = wave & 3;
    const int pf = wave >> 2;
    bf16x8 afr[4];
    const bf16* ohrow = sOh + (pm * 16 + c) * SOH_STRIDE;
    #pragma unroll
    for (int kc = 0; kc < 4; ++kc)
        afr[kc] = *(const bf16x8*)(ohrow + kc * 32 + quad * 8);

    #pragma unroll
    for (int nt = 0; nt < 4; ++nt) {
        f32x4 pacc;
        #pragma unroll
        for (int r = 0; r < 4; ++r) pacc[r] = 0.f;
        const bf16* orow = sO2t + ((pf * 4 + nt) * 16 + c) * SO2_STRIDE;
        #pragma unroll
        for (int kc = 0; kc < 4; ++kc) {
            bf16x8 bfrag = *(const bf16x8*)(orow + kc * 32 + quad * 8);
            pacc = mfma32(afr[kc], bfrag, pacc);
        }
        #pragma unroll
        for (int r = 0; r < 4; ++r) {
            int qg = q0 + pm * 16 + quad * 4 + r;
            atomicAdd(out + ((size_t)(b * L_ + qg) * F_ + (pf * 4 + nt) * 16 + c), pacc[r]);
        }
    }
}

extern "C" void kernel_launch(void* const* d_in, const int* in_sizes, int n_in,
                              void* d_out, int out_size, void* d_ws, size_t ws_size,
                              hipStream_t stream) {
    const float* XQ   = (const float*)d_in[0];
    const float* XK   = (const float*)d_in[1];
    const float* XV   = (const float*)d_in[2];
    const int*   mask = (const int*)d_in[3];
    const float* WQ   = (const float*)d_in[4];
    const float* WK   = (const float*)d_in[5];
    const float* WV   = (const float*)d_in[6];
    const float* Om   = (const float*)d_in[7];
    float* out = (float*)d_out;

    char* ws = (char*)d_ws;
    bf16* Kb   = (bf16*)(ws + WS_KB);
    bf16* Vtb  = (bf16*)(ws + WS_VT);
    u64*  bits = (u64*)(ws + WS_MB);

    prep_all<<<8704, 256, 0, stream>>>(XK, XV, mask, Kb, Vtb, bits);
    hipMemsetAsync(out, 0, (size_t)out_size * sizeof(float), stream);

    dim3 grid(L_ / QT, H_, B_);
    attn_fused_kernel<<<grid, 512, 0, stream>>>(XQ, Kb, Vtb, bits, WQ, WK, WV, Om, out);
}